// Round 1
// baseline (762.825 us; speedup 1.0000x reference)
//
#include <hip/hip_runtime.h>

#define BATCH 4096
#define SEQT  2048
#define HID   10

// fast activation helpers: v_exp_f32 + v_rcp_f32 (ulp-level error, fine at 6.6e-3 threshold)
__device__ __forceinline__ float fast_sigmoid(float v) {
    return __builtin_amdgcn_rcpf(1.0f + __expf(-v));
}
__device__ __forceinline__ float fast_tanh(float v) {
    // tanh(v) = 1 - 2/(1+e^{2v}); saturates correctly at +/-1 for large |v|
    return fmaf(-2.0f, __builtin_amdgcn_rcpf(1.0f + __expf(2.0f * v)), 1.0f);
}

// One 16-lane group per batch element. Lane j (0..9) owns hidden unit j; lanes
// 10..15 are padding with zero weights (their h stays finite, W_out=0 so they
// contribute 0 to the output reduction). 256 threads/block = 16 batch rows,
// 256 blocks -> 1024 waves -> 1 wave per SIMD across the whole chip.
__global__ __launch_bounds__(256, 1) void lstm_fused(
    const float* __restrict__ x,      // [B, T, 1]
    const float* __restrict__ W_ih,   // [4H, 1]
    const float* __restrict__ W_hh,   // [4H, H]
    const float* __restrict__ b_ih,   // [4H]
    const float* __restrict__ b_hh,   // [4H]
    const float* __restrict__ W_out,  // [1, H]
    const float* __restrict__ b_out,  // [1]
    float* __restrict__ out)          // [B, T, 1]
{
    const int tid = threadIdx.x;
    const int j   = tid & 15;                    // unit lane within group
    const int grp = tid >> 4;                    // group within block
    const int b   = blockIdx.x * 16 + grp;       // batch row
    const bool real = (j < HID);

    // per-lane weights: 4 gates (i,f,g,o) x this unit's row of W_hh
    float wih[4], bias[4], whh[4][HID];
    #pragma unroll
    for (int g = 0; g < 4; ++g) {
        const int r = g * HID + j;               // PyTorch gate order i,f,g,o
        wih[g]  = real ? W_ih[r] : 0.0f;
        bias[g] = real ? (b_ih[r] + b_hh[r]) : 0.0f;
        #pragma unroll
        for (int jp = 0; jp < HID; ++jp)
            whh[g][jp] = real ? W_hh[r * HID + jp] : 0.0f;
    }
    const float wout = real ? W_out[j] : 0.0f;
    const float bout = b_out[0];

    const float* xrow = x   + (size_t)b * SEQT;
    float*       orow = out + (size_t)b * SEQT;

    float h = 0.0f, c = 0.0f;

    // lane j prefetches x[t = tc + j]; broadcast per step via shfl
    float xv = xrow[j];
    for (int tc = 0; tc < SEQT; tc += 16) {
        const int tn = tc + 16;
        float xv_next = (tn < SEQT) ? xrow[tn + j] : 0.0f;  // prefetch next chunk
        float r_keep = 0.0f;
        #pragma unroll
        for (int s = 0; s < 16; ++s) {
            const float xt = __shfl(xv, s, 16);
            float acc0 = fmaf(xt, wih[0], bias[0]);
            float acc1 = fmaf(xt, wih[1], bias[1]);
            float acc2 = fmaf(xt, wih[2], bias[2]);
            float acc3 = fmaf(xt, wih[3], bias[3]);
            #pragma unroll
            for (int jp = 0; jp < HID; ++jp) {
                const float hb = __shfl(h, jp, 16);
                acc0 = fmaf(hb, whh[0][jp], acc0);
                acc1 = fmaf(hb, whh[1][jp], acc1);
                acc2 = fmaf(hb, whh[2][jp], acc2);
                acc3 = fmaf(hb, whh[3][jp], acc3);
            }
            const float ig = fast_sigmoid(acc0);
            const float fg = fast_sigmoid(acc1);
            const float gg = fast_tanh(acc2);
            const float og = fast_sigmoid(acc3);
            c = fmaf(fg, c, ig * gg);
            h = og * fast_tanh(c);

            // out[b,t] = sum_j h_j * wout_j  (+bout at store)
            float r = h * wout;
            r += __shfl_xor(r, 1, 16);
            r += __shfl_xor(r, 2, 16);
            r += __shfl_xor(r, 4, 16);
            r += __shfl_xor(r, 8, 16);
            r_keep = (s == j) ? r : r_keep;      // lane j keeps step tc+j
        }
        orow[tc + j] = r_keep + bout;            // coalesced 16-float store
        xv = xv_next;
    }
}

extern "C" void kernel_launch(void* const* d_in, const int* in_sizes, int n_in,
                              void* d_out, int out_size, void* d_ws, size_t ws_size,
                              hipStream_t stream) {
    const float* x     = (const float*)d_in[0];
    const float* W_ih  = (const float*)d_in[1];
    const float* W_hh  = (const float*)d_in[2];
    const float* b_ih  = (const float*)d_in[3];
    const float* b_hh  = (const float*)d_in[4];
    const float* W_out = (const float*)d_in[5];
    const float* b_out = (const float*)d_in[6];
    float* out = (float*)d_out;

    dim3 grid(BATCH / 16);   // 256 blocks, 16 batch rows each
    dim3 block(256);
    lstm_fused<<<grid, block, 0, stream>>>(x, W_ih, W_hh, b_ih, b_hh,
                                           W_out, b_out, out);
}

// Round 2
// 487.181 us; speedup vs baseline: 1.5658x; 1.5658x over previous
//
#include <hip/hip_runtime.h>

#define BATCH 4096
#define SEQT  2048
#define HID   10

typedef float v2f __attribute__((ext_vector_type(2)));

// fast activations: v_exp_f32 + v_rcp_f32 (measured absmax 9.8e-4 vs 6.6e-3 threshold)
__device__ __forceinline__ float fast_sigmoid(float v) {
    return __builtin_amdgcn_rcpf(1.0f + __expf(-v));
}
__device__ __forceinline__ float fast_tanh(float v) {
    return fmaf(-2.0f, __builtin_amdgcn_rcpf(1.0f + __expf(2.0f * v)), 1.0f);
}

// One 16-lane group per batch row; lane j owns hidden unit j (j>=10: zero
// weights, h stays exactly 0). h broadcast via LDS write+read (4 LDS ops/step
// vs 15 bpermute/swizzle before). Output dot computed redundantly per-lane
// from the hv regs already loaded for the gate matvec -> no cross-lane
// reduction on the critical path. 1024 waves = 1 wave/SIMD chip-wide.
__global__ __launch_bounds__(256, 1) void lstm_fused(
    const float* __restrict__ x,      // [B, T, 1]
    const float* __restrict__ W_ih,   // [4H, 1]
    const float* __restrict__ W_hh,   // [4H, H]
    const float* __restrict__ b_ih,   // [4H]
    const float* __restrict__ b_hh,   // [4H]
    const float* __restrict__ W_out,  // [1, H]
    const float* __restrict__ b_out,  // [1]
    float* __restrict__ out)          // [B, T, 1]
{
    __shared__ float hsh[16 * 16];               // [group][lane]

    const int tid = threadIdx.x;
    const int j   = tid & 15;
    const int grp = tid >> 4;
    const int b   = blockIdx.x * 16 + grp;
    const bool real = (j < HID);

    float* hbase = &hsh[grp * 16];               // 64B aligned -> b128 ok

    // per-lane weights; packed as float2 pairs for v_pk_fma_f32
    float wih[4], bias[4];
    v2f whh[4][5];
    #pragma unroll
    for (int g = 0; g < 4; ++g) {
        const int r = g * HID + j;               // PyTorch gate order i,f,g,o
        wih[g]  = real ? W_ih[r] : 0.0f;
        bias[g] = real ? (b_ih[r] + b_hh[r]) : 0.0f;
        #pragma unroll
        for (int p = 0; p < 5; ++p) {
            whh[g][p].x = real ? W_hh[r * HID + 2 * p]     : 0.0f;
            whh[g][p].y = real ? W_hh[r * HID + 2 * p + 1] : 0.0f;
        }
    }
    v2f wout[5];
    #pragma unroll
    for (int p = 0; p < 5; ++p) {
        wout[p].x = W_out[2 * p];
        wout[p].y = W_out[2 * p + 1];
    }
    const float bout = b_out[0];

    const float* xrow = x   + (size_t)b * SEQT;
    float*       orow = out + (size_t)b * SEQT;

    float h = 0.0f, c = 0.0f, r_keep = 0.0f;

    // x: same-address float4 loads (L1 broadcast), prefetched one chunk ahead
    float4 xc0, xc1, xc2, xc3;
    {
        const float4* xp = (const float4*)xrow;
        xc0 = xp[0]; xc1 = xp[1]; xc2 = xp[2]; xc3 = xp[3];
    }

    for (int tc = 0; tc < SEQT; tc += 16) {
        float4 xn0, xn1, xn2, xn3;
        if (tc + 16 < SEQT) {
            const float4* xp = (const float4*)(xrow + tc + 16);
            xn0 = xp[0]; xn1 = xp[1]; xn2 = xp[2]; xn3 = xp[3];
        } else {
            xn0 = xn1 = xn2 = xn3 = make_float4(0.f, 0.f, 0.f, 0.f);
        }
        const float xs[16] = {xc0.x, xc0.y, xc0.z, xc0.w,
                              xc1.x, xc1.y, xc1.z, xc1.w,
                              xc2.x, xc2.y, xc2.z, xc2.w,
                              xc3.x, xc3.y, xc3.z, xc3.w};
        #pragma unroll
        for (int s = 0; s < 16; ++s) {
            // h_{t-1} broadcast: 1 write + 3 reads, same-wave in-order LDS pipe
            hbase[j] = h;
            const float4 ha = ((const float4*)hbase)[0];     // h0..h3
            const float4 hb = ((const float4*)hbase)[1];     // h4..h7
            const float2 hc = ((const float2*)hbase)[4];     // h8..h9
            v2f hp[5];
            hp[0] = v2f{ha.x, ha.y}; hp[1] = v2f{ha.z, ha.w};
            hp[2] = v2f{hb.x, hb.y}; hp[3] = v2f{hb.z, hb.w};
            hp[4] = v2f{hc.x, hc.y};

            // out[t-1] = dot(h_{t-1}, W_out) — redundant per-lane, no xlane ops
            v2f rd = v2f{0.f, 0.f};
            #pragma unroll
            for (int p = 0; p < 5; ++p)
                rd = __builtin_elementwise_fma(hp[p], wout[p], rd);
            const float r = rd.x + rd.y + bout;
            // lane (t-1)&15 keeps r;  s refers to t = tc + s
            if (j == ((s + 15) & 15)) r_keep = r;
            if (s == 0 && tc > 0) orow[tc - 16 + j] = r_keep;  // prev chunk

            // gate matvec: 4 gates x 5 packed fmas
            v2f a0 = v2f{0.f, 0.f}, a1 = a0, a2 = a0, a3 = a0;
            #pragma unroll
            for (int p = 0; p < 5; ++p) {
                a0 = __builtin_elementwise_fma(hp[p], whh[0][p], a0);
                a1 = __builtin_elementwise_fma(hp[p], whh[1][p], a1);
                a2 = __builtin_elementwise_fma(hp[p], whh[2][p], a2);
                a3 = __builtin_elementwise_fma(hp[p], whh[3][p], a3);
            }
            const float xt = xs[s];
            const float g0 = fmaf(xt, wih[0], bias[0]) + a0.x + a0.y;
            const float g1 = fmaf(xt, wih[1], bias[1]) + a1.x + a1.y;
            const float g2 = fmaf(xt, wih[2], bias[2]) + a2.x + a2.y;
            const float g3 = fmaf(xt, wih[3], bias[3]) + a3.x + a3.y;

            const float ig = fast_sigmoid(g0);
            const float fg = fast_sigmoid(g1);
            const float gg = fast_tanh(g2);
            const float og = fast_sigmoid(g3);
            c = fmaf(fg, c, ig * gg);
            h = og * fast_tanh(c);
        }
        xc0 = xn0; xc1 = xn1; xc2 = xn2; xc3 = xn3;
    }

    // epilogue: out[T-1] needs h_{T-1}
    {
        hbase[j] = h;
        const float4 ha = ((const float4*)hbase)[0];
        const float4 hb = ((const float4*)hbase)[1];
        const float2 hc = ((const float2*)hbase)[4];
        v2f hp[5];
        hp[0] = v2f{ha.x, ha.y}; hp[1] = v2f{ha.z, ha.w};
        hp[2] = v2f{hb.x, hb.y}; hp[3] = v2f{hb.z, hb.w};
        hp[4] = v2f{hc.x, hc.y};
        v2f rd = v2f{0.f, 0.f};
        #pragma unroll
        for (int p = 0; p < 5; ++p)
            rd = __builtin_elementwise_fma(hp[p], wout[p], rd);
        const float r = rd.x + rd.y + bout;
        if (j == 15) r_keep = r;                  // (T-1) & 15 == 15
        orow[SEQT - 16 + j] = r_keep;             // final chunk
    }
}

extern "C" void kernel_launch(void* const* d_in, const int* in_sizes, int n_in,
                              void* d_out, int out_size, void* d_ws, size_t ws_size,
                              hipStream_t stream) {
    const float* x     = (const float*)d_in[0];
    const float* W_ih  = (const float*)d_in[1];
    const float* W_hh  = (const float*)d_in[2];
    const float* b_ih  = (const float*)d_in[3];
    const float* b_hh  = (const float*)d_in[4];
    const float* W_out = (const float*)d_in[5];
    const float* b_out = (const float*)d_in[6];
    float* out = (float*)d_out;

    dim3 grid(BATCH / 16);   // 256 blocks x 16 rows
    dim3 block(256);
    lstm_fused<<<grid, block, 0, stream>>>(x, W_ih, W_hh, b_ih, b_hh,
                                           W_out, b_out, out);
}